// Round 9
// baseline (576.521 us; speedup 1.0000x reference)
//
#include <hip/hip_runtime.h>
#include <math.h>

// ReAttention round 9: wave-private attention core. Operand-swapped QK
// (A=K, B=Q -> D[m][n]) puts all 8 heads' exps for the same (n,m) positions
// in the same lane AND in PV's A-fragment layout -> conv mix in registers,
// PV via mfma 16x16x16. ZERO in-loop LDS/barriers in k_rsum/k_fuse.
// B=8 N=1024 D=512 H=8 dh=64.
//
//  - conv bias cancels in train-mode BN; E[u_g] = sum_h c_gh / N analytic
//    (softmax rows sum to 1) -> only sum(u^2) accumulated on device.
//  - attn'' = alpha_g*u_g + c_g ; out_inner = alpha_g*O1 + c_g*vsum.
//  - R5 lesson: spill shows up as phantom WRITE_SIZE. R8 lesson: cross-wave
//    S handoff (LDS or HBM) is the structural bottleneck -> eliminated.

#define Bz 8
#define Nn 1024
#define Dd 512
#define Hh 8
#define DH 64
#define INNER 512
#define QW 1536
#define SCALE 0.125f
#define BN_EPS 1e-5f

typedef _Float16 __f16;
typedef __f16 f16x8 __attribute__((ext_vector_type(8)));
typedef __f16 f16x4 __attribute__((ext_vector_type(4)));
typedef float f32x4 __attribute__((ext_vector_type(4)));

#define MFMA16(a, b, c) __builtin_amdgcn_mfma_f32_16x16x32_f16((a), (b), (c), 0, 0, 0)
#define MFMA16K16(a, b, c) __builtin_amdgcn_mfma_f32_16x16x16f16((a), (b), (c), 0, 0, 0)

__device__ __forceinline__ unsigned short f2h(float f) {
  union { __f16 h; unsigned short s; } v;
  v.h = (__f16)f;
  return v.s;
}
__device__ __forceinline__ float h2f(unsigned short s) {
  union { unsigned short s; __f16 h; } v;
  v.s = s;
  return (float)v.h;
}

// ws layout (bytes) — flat, no overlays. total ~86.3 MB
#define WB_XB 0u                        // 8,388,608
#define WB_QKV 8388608u                 // 25,165,824
#define WB_VT 33554432u                 // 8,388,608
#define WB_O1A 41943040u                // 16,777,216 fp32
#define WB_O1B 58720256u                // 16,777,216 fp32
#define WB_O1BF 75497472u               // 8,388,608 fp16
#define WB_WQT 83886080u                // 1,572,864
#define WB_WOT 85458944u                // 524,288
#define WB_RINV 85983232u               // 262,144
#define WB_VSUM 86245376u               // 16,384
#define WB_STATS 86261760u              // 64
#define WB_AC 86261824u                 // 64

// ---------------- x -> fp16 ------------------------------------------------
__global__ __launch_bounds__(256) void k_xbf(const float* __restrict__ X,
                                             unsigned short* __restrict__ XB) {
  const size_t i = ((size_t)blockIdx.x * 256 + threadIdx.x) * 8;
  float4 f0 = *(const float4*)(X + i);
  float4 f1 = *(const float4*)(X + i + 4);
  unsigned short o[8] = {f2h(f0.x), f2h(f0.y), f2h(f0.z), f2h(f0.w),
                         f2h(f1.x), f2h(f1.y), f2h(f1.z), f2h(f1.w)};
  *(uint4*)(XB + i) = *(uint4*)o;
}

// ---------------- transpose fp32 -> fp16: dst[C][R] = src[R][C]^T ----------
__global__ __launch_bounds__(256) void k_transpose(const float* __restrict__ src,
                                                   unsigned short* __restrict__ dst,
                                                   int R, int C) {
  __shared__ float tile[32][33];
  const int tc = blockIdx.x * 32, tr = blockIdx.y * 32;
  const int lx = threadIdx.x & 31, ly = threadIdx.x >> 5;
#pragma unroll
  for (int i = 0; i < 32; i += 8)
    tile[ly + i][lx] = src[(size_t)(tr + ly + i) * C + tc + lx];
  __syncthreads();
#pragma unroll
  for (int i = 0; i < 32; i += 8)
    dst[(size_t)(tc + ly + i) * R + tr + lx] = f2h(tile[lx][ly + i]);
}

// ---------------- K0: qkv = x @ w_qkv (fp16 MFMA) --------------------------
__global__ __launch_bounds__(256) void k_qkv(const unsigned short* __restrict__ XB,
                                             const unsigned short* __restrict__ WQT,
                                             unsigned short* __restrict__ qkv,
                                             unsigned short* __restrict__ vT) {
  extern __shared__ char smem[];
  unsigned short(*sA)[40] = (unsigned short(*)[40])smem;
  unsigned short(*sB)[40] = (unsigned short(*)[40])(smem + 128 * 40 * 2);
  unsigned short* sEp = (unsigned short*)smem;  // 128*136 after loop
  const int t = threadIdx.x;
  const int col0 = blockIdx.x * 128;
  const int row0 = blockIdx.y * 128;
  const bool isqk = (col0 < 2 * INNER);
  const int l = t & 63, w = t >> 6;
  const int wm = (w & 1) * 64, wn = (w >> 1) * 64;
  const int lm = l & 15, lq = l >> 4;
  const int srow = t >> 1, skc = (t & 1) * 16;
  f32x4 acc[4][4] = {};
  for (int k0 = 0; k0 < Dd; k0 += 32) {
    {
      const unsigned short* src = XB + (size_t)(row0 + srow) * Dd + k0 + skc;
      *(uint4*)&sA[srow][skc] = *(const uint4*)src;
      *(uint4*)&sA[srow][skc + 8] = *(const uint4*)(src + 8);
    }
    {
      const unsigned short* srcB = WQT + (size_t)(col0 + srow) * Dd + k0 + skc;
      *(uint4*)&sB[srow][skc] = *(const uint4*)srcB;
      *(uint4*)&sB[srow][skc + 8] = *(const uint4*)(srcB + 8);
    }
    __syncthreads();
    f16x8 af[4], bfr[4];
#pragma unroll
    for (int i = 0; i < 4; i++) af[i] = *(const f16x8*)&sA[wm + 16 * i + lm][lq * 8];
#pragma unroll
    for (int j = 0; j < 4; j++) bfr[j] = *(const f16x8*)&sB[wn + 16 * j + lm][lq * 8];
    if (isqk) {
#pragma unroll
      for (int i = 0; i < 4; i++)
#pragma unroll
        for (int j = 0; j < 4; j++) acc[i][j] = MFMA16(bfr[i], af[j], acc[i][j]);
    } else {
#pragma unroll
      for (int i = 0; i < 4; i++)
#pragma unroll
        for (int j = 0; j < 4; j++) acc[i][j] = MFMA16(af[i], bfr[j], acc[i][j]);
    }
    __syncthreads();
  }
  if (isqk) {
#pragma unroll
    for (int jc = 0; jc < 4; jc++)
#pragma unroll
      for (int ir = 0; ir < 4; ir++) {
        unsigned short us[4];
#pragma unroll
        for (int r = 0; r < 4; r++) us[r] = f2h(acc[jc][ir][r]);
        *(uint2*)&sEp[(wm + 16 * ir + lm) * 136 + wn + 16 * jc + 4 * lq] = *(uint2*)us;
      }
    __syncthreads();
    const int row = t >> 1, half = t & 1;
    const unsigned short* src = &sEp[row * 136 + half * 64];
    unsigned short* dst = qkv + (size_t)(row0 + row) * QW + col0 + half * 64;
#pragma unroll
    for (int c = 0; c < 8; c++) *(uint4*)(dst + c * 8) = *(const uint4*)(src + c * 8);
  } else {
#pragma unroll
    for (int ir = 0; ir < 4; ir++)
#pragma unroll
      for (int jc = 0; jc < 4; jc++) {
        unsigned short us[4];
#pragma unroll
        for (int r = 0; r < 4; r++) us[r] = f2h(acc[ir][jc][r]);
        *(uint2*)&sEp[(wn + 16 * jc + lm) * 136 + wm + 16 * ir + 4 * lq] = *(uint2*)us;
      }
    __syncthreads();
    const int row = t >> 1, half = t & 1;
    const int gd = col0 - 2 * INNER + row;
    const int bq = row0 >> 10, mseq0 = row0 & 1023;
    const unsigned short* src = &sEp[row * 136 + half * 64];
    unsigned short* dst =
        vT + (((size_t)(bq * Hh + (gd >> 6)) * DH + (gd & 63)) << 10) + mseq0 + half * 64;
#pragma unroll
    for (int c = 0; c < 8; c++) *(uint4*)(dst + c * 8) = *(const uint4*)(src + c * 8);
  }
}

// ---------------- k_vsum --------------------------------------------------
__global__ __launch_bounds__(256) void k_vsum(const unsigned short* __restrict__ vT,
                                              float* __restrict__ vsum) {
  const int bg = blockIdx.x;
  const int d = threadIdx.x >> 2, qq = threadIdx.x & 3;
  __shared__ float red[64][4];
  const unsigned short* p = vT + ((size_t)bg * DH + d) * Nn + qq * 256;
  float s = 0.f;
  for (int m = 0; m < 256; m += 4) {
    uint2 rr = *(const uint2*)(p + m);
    s += h2f((unsigned short)(rr.x & 0xffff)) + h2f((unsigned short)(rr.x >> 16)) +
         h2f((unsigned short)(rr.y & 0xffff)) + h2f((unsigned short)(rr.y >> 16));
  }
  red[d][qq] = s;
  __syncthreads();
  if (threadIdx.x < 64)
    vsum[(size_t)bg * DH + threadIdx.x] =
        red[threadIdx.x][0] + red[threadIdx.x][1] + red[threadIdx.x][2] + red[threadIdx.x][3];
}

// ---------------- kA: rinv (wave-private, 1 barrier total) ----------------
// grid (b=8, nt=64); 512 thr = 8 waves; wave w = m-eighth, all 8 heads.
// Operand-swapped QK: D[m][n] -> lane lm = n, rows lq*4+r = m.
__global__ __launch_bounds__(512, 4) void k_rsum(const unsigned short* __restrict__ qkv,
                                                 float* __restrict__ rinv) {
  __shared__ float sRed[8][8][16];  // [wave][h][n] 4 KB
  const int b = blockIdx.x;
  const int n0 = blockIdx.y * 16;
  const int t = threadIdx.x;
  const int w = t >> 6, l = t & 63;
  const int lm = l & 15, lq = l >> 4;
  f16x8 qf[8][2];
#pragma unroll
  for (int h = 0; h < 8; h++) {
    const unsigned short* qp = qkv + (size_t)(b * Nn + n0 + lm) * QW + h * DH + lq * 8;
    qf[h][0] = *(const f16x8*)qp;
    qf[h][1] = *(const f16x8*)(qp + 32);
  }
  float psum[8] = {};
  for (int it = 0; it < 8; it++) {
    const int m0 = w * 16 + it * 128;
    const unsigned short* kbase = qkv + (size_t)(b * Nn + m0 + lm) * QW + INNER + lq * 8;
#pragma unroll
    for (int h = 0; h < 8; h++) {
      f16x8 k0 = *(const f16x8*)(kbase + h * DH);
      f16x8 k1 = *(const f16x8*)(kbase + h * DH + 32);
      f32x4 lac = {};
      lac = MFMA16(k0, qf[h][0], lac);
      lac = MFMA16(k1, qf[h][1], lac);
#pragma unroll
      for (int r = 0; r < 4; r++) psum[h] += __expf(lac[r] * SCALE);
    }
  }
#pragma unroll
  for (int h = 0; h < 8; h++) {
    float p = psum[h];
    p += __shfl_xor(p, 16);
    p += __shfl_xor(p, 32);
    if (lq == 0) sRed[w][h][lm] = p;
  }
  __syncthreads();
  if (t < 128) {
    const int h = t >> 4, n = t & 15;
    float s = 0.f;
#pragma unroll
    for (int ww = 0; ww < 8; ww++) s += sRed[ww][h][n];
    rinv[(size_t)(b * Hh + h) * Nn + n0 + n] = 1.0f / s;
  }
}

// ---------------- kB: QK+mix+su2+PV, fully wave-private --------------------
// grid (b=8, nt=64, ms=2); 128 thr = 2 waves = 2 g-halves (same m-range).
// NO LDS, NO barriers. O1 partial (per ms) -> O1A/O1B, summed in k_o1aff.
__global__ __launch_bounds__(128, 2) void k_fuse(const unsigned short* __restrict__ qkv,
                                                 const unsigned short* __restrict__ vT,
                                                 const float* __restrict__ rinv,
                                                 const float* __restrict__ conv_w,
                                                 float* __restrict__ O1A,
                                                 float* __restrict__ O1B,
                                                 float* __restrict__ stats) {
  const int b = blockIdx.x;
  const int n0 = blockIdx.y * 16;
  const int ms = blockIdx.z;
  float* __restrict__ O1 = ms ? O1B : O1A;
  const int t = threadIdx.x;
  const int l = t & 63, lm = l & 15, lq = l >> 4;
  const int ghu = __builtin_amdgcn_readfirstlane(t >> 6);  // wave-uniform g-half
  // conv_w rows for this wave's 4 g -> SGPRs (uniform literal-indexed loads)
  float cw[32];
  if (ghu == 0) {
#pragma unroll
    for (int i = 0; i < 32; i++) cw[i] = conv_w[i];
  } else {
#pragma unroll
    for (int i = 0; i < 32; i++) cw[i] = conv_w[32 + i];
  }
  float rv[8];
#pragma unroll
  for (int h = 0; h < 8; h++) rv[h] = rinv[(size_t)(b * Hh + h) * Nn + n0 + lm];
  f16x8 qf[8][2];
#pragma unroll
  for (int h = 0; h < 8; h++) {
    const unsigned short* qp = qkv + (size_t)(b * Nn + n0 + lm) * QW + h * DH + lq * 8;
    qf[h][0] = *(const f16x8*)qp;
    qf[h][1] = *(const f16x8*)(qp + 32);
  }
  f32x4 acc[4][4] = {};  // [g-local][d-tile]
  float su2[4] = {};
  for (int it = 0; it < 32; it++) {
    const int m0 = ms * 512 + it * 16;
    const unsigned short* kbase = qkv + (size_t)(b * Nn + m0 + lm) * QW + INNER + lq * 8;
    float u[4][4] = {};  // [g-local][r]
#pragma unroll
    for (int h = 0; h < 8; h++) {
      f16x8 k0 = *(const f16x8*)(kbase + h * DH);
      f16x8 k1 = *(const f16x8*)(kbase + h * DH + 32);
      f32x4 lac = {};
      lac = MFMA16(k0, qf[h][0], lac);  // D[m=lq*4+r][n=lm]
      lac = MFMA16(k1, qf[h][1], lac);
      float s[4];
#pragma unroll
      for (int r = 0; r < 4; r++) s[r] = __expf(lac[r] * SCALE) * rv[h];
#pragma unroll
      for (int gl = 0; gl < 4; gl++)
#pragma unroll
        for (int r = 0; r < 4; r++) u[gl][r] += cw[gl * 8 + h] * s[r];
    }
#pragma unroll
    for (int gl = 0; gl < 4; gl++) {
      su2[gl] += u[gl][0] * u[gl][0] + u[gl][1] * u[gl][1] + u[gl][2] * u[gl][2] +
                 u[gl][3] * u[gl][3];
      f16x4 up = {(__f16)u[gl][0], (__f16)u[gl][1], (__f16)u[gl][2], (__f16)u[gl][3]};
      const int g = ghu * 4 + gl;
      const unsigned short* vb =
          vT + (((size_t)(b * Hh + g) * DH + lm) << 10) + m0 + lq * 4;
#pragma unroll
      for (int dt = 0; dt < 4; dt++) {
        f16x4 vf = *(const f16x4*)(vb + ((size_t)dt << 14));  // dt*16*1024
        acc[gl][dt] = MFMA16K16(up, vf, acc[gl][dt]);  // D[n][d]
      }
    }
  }
  // O1 write: n = n0+lq*4+r, d = dt*16+lm
#pragma unroll
  for (int gl = 0; gl < 4; gl++) {
    const int g = ghu * 4 + gl;
#pragma unroll
    for (int dt = 0; dt < 4; dt++)
#pragma unroll
      for (int r = 0; r < 4; r++)
        O1[((size_t)(b * Hh + g) * Nn + n0 + lq * 4 + r) * DH + dt * 16 + lm] =
            acc[gl][dt][r];
  }
#pragma unroll
  for (int gl = 0; gl < 4; gl++) {
    float q = su2[gl];
    for (int off = 32; off; off >>= 1) q += __shfl_down(q, off);
    if (l == 0) atomicAdd(&stats[ghu * 4 + gl], q);
  }
}

// ---------------- K3: alpha/const (E[u] analytic) --------------------------
__global__ void k_alpha(const float* __restrict__ stats, const float* __restrict__ conv_w,
                        const float* __restrict__ bn_gamma,
                        const float* __restrict__ bn_beta, float* __restrict__ ac) {
  const int g = threadIdx.x;
  if (g < 8) {
    float csum = 0.f;
#pragma unroll
    for (int h = 0; h < 8; h++) csum += conv_w[g * 8 + h];
    const float Eu = csum / (float)Nn;  // rows of softmax sum to 1
    const float cnt = (float)Bz * (float)Nn * (float)Nn;
    float Eu2 = stats[g] / cnt;
    float inv = rsqrtf(Eu2 - Eu * Eu + BN_EPS);
    float alpha = bn_gamma[g] * inv;
    ac[g] = alpha;
    ac[8 + g] = bn_beta[g] - Eu * alpha;
  }
}

// ---------------- k_o1aff: O1hf = fp16(alpha*(O1A+O1B) + c*vsum) -----------
__global__ __launch_bounds__(256) void k_o1aff(const float* __restrict__ O1A,
                                               const float* __restrict__ O1B,
                                               const float* __restrict__ vsum,
                                               const float* __restrict__ ac,
                                               unsigned short* __restrict__ O1BF) {
  const size_t i4 = ((size_t)blockIdx.x * 256 + threadIdx.x) * 4;
  const int bg = (int)(i4 >> 16);
  const int g = bg & 7;
  const int d = (int)(i4 & 63);
  float4 a = *(const float4*)(O1A + i4);
  float4 bb = *(const float4*)(O1B + i4);
  float4 v = *(const float4*)(vsum + (size_t)bg * DH + d);
  const float al = ac[g], cc = ac[8 + g];
  unsigned short o[4] = {f2h(al * (a.x + bb.x) + cc * v.x), f2h(al * (a.y + bb.y) + cc * v.y),
                         f2h(al * (a.z + bb.z) + cc * v.z), f2h(al * (a.w + bb.w) + cc * v.w)};
  *(uint2*)(O1BF + i4) = *(uint2*)o;
}

// ---------------- K4: out = O1hf @ w_out + b_out (fp16 MFMA) ---------------
__global__ __launch_bounds__(256) void k_out(const unsigned short* __restrict__ O1BF,
                                             const unsigned short* __restrict__ WOT,
                                             const float* __restrict__ bout,
                                             float* __restrict__ out) {
  __shared__ unsigned short sA[128][40];
  __shared__ unsigned short sB[128][40];
  const int t = threadIdx.x;
  const int col0 = blockIdx.x * 128, row0 = blockIdx.y * 128;
  const int l = t & 63, w = t >> 6;
  const int wm = (w & 1) * 64, wn = (w >> 1) * 64;
  const int lm = l & 15, lq = l >> 4;
  const int srow = t >> 1, skc = (t & 1) * 16;
  const int b = row0 >> 10;
  const int nn = (row0 + srow) & 1023;
  f32x4 acc[4][4] = {};
  for (int k0 = 0; k0 < INNER; k0 += 32) {
    {
      const int k = k0 + skc;
      const int g = k >> 6, dd = k & 63;
      const unsigned short* src = O1BF + ((size_t)(b * Hh + g) * Nn + nn) * DH + dd;
      *(uint4*)&sA[srow][skc] = *(const uint4*)src;
      *(uint4*)&sA[srow][skc + 8] = *(const uint4*)(src + 8);
    }
    {
      const unsigned short* srcB = WOT + (size_t)(col0 + srow) * INNER + k0 + skc;
      *(uint4*)&sB[srow][skc] = *(const uint4*)srcB;
      *(uint4*)&sB[srow][skc + 8] = *(const uint4*)(srcB + 8);
    }
    __syncthreads();
    f16x8 af[4], bfr[4];
#pragma unroll
    for (int i = 0; i < 4; i++) af[i] = *(const f16x8*)&sA[wm + 16 * i + lm][lq * 8];
#pragma unroll
    for (int j = 0; j < 4; j++) bfr[j] = *(const f16x8*)&sB[wn + 16 * j + lm][lq * 8];
#pragma unroll
    for (int i = 0; i < 4; i++)
#pragma unroll
      for (int j = 0; j < 4; j++) acc[i][j] = MFMA16(af[i], bfr[j], acc[i][j]);
    __syncthreads();
  }
#pragma unroll
  for (int j = 0; j < 4; j++) {
    const int col = col0 + wn + 16 * j + lm;
    const float bo = bout[col];
#pragma unroll
    for (int i = 0; i < 4; i++) {
      const int rbase = row0 + wm + 16 * i + lq * 4;
#pragma unroll
      for (int r = 0; r < 4; r++) out[(size_t)(rbase + r) * Dd + col] = acc[i][j][r] + bo;
    }
  }
}

extern "C" void kernel_launch(void* const* d_in, const int* in_sizes, int n_in,
                              void* d_out, int out_size, void* d_ws, size_t ws_size,
                              hipStream_t stream) {
  const float* x = (const float*)d_in[0];
  const float* w_qkv = (const float*)d_in[1];
  const float* conv_w = (const float*)d_in[2];
  // d_in[3] = conv_b : cancels in train-mode BN.
  const float* bn_gamma = (const float*)d_in[4];
  const float* bn_beta = (const float*)d_in[5];
  const float* w_out = (const float*)d_in[6];
  const float* b_out = (const float*)d_in[7];
  char* ws = (char*)d_ws;
  unsigned short* XB = (unsigned short*)(ws + WB_XB);
  unsigned short* QKV = (unsigned short*)(ws + WB_QKV);
  unsigned short* VT = (unsigned short*)(ws + WB_VT);
  unsigned short* WQT = (unsigned short*)(ws + WB_WQT);
  unsigned short* WOT = (unsigned short*)(ws + WB_WOT);
  float* O1Ap = (float*)(ws + WB_O1A);
  float* O1Bp = (float*)(ws + WB_O1B);
  unsigned short* O1BF = (unsigned short*)(ws + WB_O1BF);
  float* RINV = (float*)(ws + WB_RINV);
  float* VSUM = (float*)(ws + WB_VSUM);
  float* STATS = (float*)(ws + WB_STATS);
  float* AC = (float*)(ws + WB_AC);

  hipMemsetAsync(STATS, 0, 64, stream);
  k_xbf<<<2048, 256, 0, stream>>>(x, XB);
  k_transpose<<<dim3(48, 16), 256, 0, stream>>>(w_qkv, WQT, 512, 1536);
  k_transpose<<<dim3(16, 16), 256, 0, stream>>>(w_out, WOT, 512, 512);
  k_qkv<<<dim3(12, 64), 256, 34816, stream>>>(XB, WQT, QKV, VT);
  k_vsum<<<64, 256, 0, stream>>>(VT, VSUM);
  k_rsum<<<dim3(8, 64), 512, 0, stream>>>(QKV, RINV);
  k_fuse<<<dim3(8, 64, 2), 128, 0, stream>>>(QKV, VT, RINV, conv_w, O1Ap, O1Bp, STATS);
  k_alpha<<<1, 64, 0, stream>>>(STATS, conv_w, bn_gamma, bn_beta, AC);
  k_o1aff<<<4096, 256, 0, stream>>>(O1Ap, O1Bp, VSUM, AC, O1BF);
  k_out<<<dim3(4, 64), 256, 0, stream>>>(O1BF, WOT, b_out, (float*)d_out);
}

// Round 10
// 336.520 us; speedup vs baseline: 1.7132x; 1.7132x over previous
//
#include <hip/hip_runtime.h>
#include <math.h>

// ReAttention round 10: merged attention core done right.
// k_rsum (R8's validated zero-LDS rowsum) + k_fuse2: QK->exp->sS | mix->sU |
// PV, with 2 barriers per 128-m chunk (17 total), vectorized LDS only,
// ~90 VGPR, 2 blocks/CU. O1 written fp16; BN affine fused into k_out.
// fp16 pipeline, fp32 accum/stats. B=8 N=1024 D=512 H=8 dh=64.
//
//  - conv bias cancels in train-mode BN; E[u_g] = sum_h c_gh/N analytic.
//  - attn'' = alpha_g*u_g + c_g ; out_inner = alpha_g*O1 + c_g*vsum.
//  - Ledger: R5 spill->phantom WRITE; R7 L3 handoff dead; R8 barrier/32m +
//    scalar LDS dead; R9 VGPR-starved latency dead. This = R6 shape,
//    4x barrier spacing, vector LDS, small regs.

#define Bz 8
#define Nn 1024
#define Dd 512
#define Hh 8
#define DH 64
#define INNER 512
#define QW 1536
#define SCALE 0.125f
#define BN_EPS 1e-5f

typedef _Float16 __f16;
typedef __f16 f16x8 __attribute__((ext_vector_type(8)));
typedef float f32x4 __attribute__((ext_vector_type(4)));

#define MFMA16(a, b, c) __builtin_amdgcn_mfma_f32_16x16x32_f16((a), (b), (c), 0, 0, 0)

__device__ __forceinline__ unsigned short f2h(float f) {
  union { __f16 h; unsigned short s; } v;
  v.h = (__f16)f;
  return v.s;
}
__device__ __forceinline__ float h2f(unsigned short s) {
  union { unsigned short s; __f16 h; } v;
  v.s = s;
  return (float)v.h;
}

// ws layout (bytes) — flat. total ~52.7 MB
#define WB_XB 0u                        // 8,388,608
#define WB_QKV 8388608u                 // 25,165,824
#define WB_VT 33554432u                 // 8,388,608
#define WB_O1H 41943040u                // 8,388,608 fp16
#define WB_WQT 50331648u                // 1,572,864
#define WB_WOT 51904512u                // 524,288
#define WB_RINV 52428800u               // 262,144
#define WB_VSUM 52690944u               // 16,384
#define WB_STATS 52707328u              // 64
#define WB_AC 52707392u                 // 64

// ---------------- x -> fp16 ------------------------------------------------
__global__ __launch_bounds__(256) void k_xbf(const float* __restrict__ X,
                                             unsigned short* __restrict__ XB) {
  const size_t i = ((size_t)blockIdx.x * 256 + threadIdx.x) * 8;
  float4 f0 = *(const float4*)(X + i);
  float4 f1 = *(const float4*)(X + i + 4);
  unsigned short o[8] = {f2h(f0.x), f2h(f0.y), f2h(f0.z), f2h(f0.w),
                         f2h(f1.x), f2h(f1.y), f2h(f1.z), f2h(f1.w)};
  *(uint4*)(XB + i) = *(uint4*)o;
}

// ---------------- transpose fp32 -> fp16: dst[C][R] = src[R][C]^T ----------
__global__ __launch_bounds__(256) void k_transpose(const float* __restrict__ src,
                                                   unsigned short* __restrict__ dst,
                                                   int R, int C) {
  __shared__ float tile[32][33];
  const int tc = blockIdx.x * 32, tr = blockIdx.y * 32;
  const int lx = threadIdx.x & 31, ly = threadIdx.x >> 5;
#pragma unroll
  for (int i = 0; i < 32; i += 8)
    tile[ly + i][lx] = src[(size_t)(tr + ly + i) * C + tc + lx];
  __syncthreads();
#pragma unroll
  for (int i = 0; i < 32; i += 8)
    dst[(size_t)(tc + ly + i) * R + tr + lx] = f2h(tile[lx][ly + i]);
}

// ---------------- K0: qkv = x @ w_qkv (fp16 MFMA) --------------------------
__global__ __launch_bounds__(256) void k_qkv(const unsigned short* __restrict__ XB,
                                             const unsigned short* __restrict__ WQT,
                                             unsigned short* __restrict__ qkv,
                                             unsigned short* __restrict__ vT) {
  extern __shared__ char smem[];
  unsigned short(*sA)[40] = (unsigned short(*)[40])smem;
  unsigned short(*sB)[40] = (unsigned short(*)[40])(smem + 128 * 40 * 2);
  unsigned short* sEp = (unsigned short*)smem;  // 128*136 after loop
  const int t = threadIdx.x;
  const int col0 = blockIdx.x * 128;
  const int row0 = blockIdx.y * 128;
  const bool isqk = (col0 < 2 * INNER);
  const int l = t & 63, w = t >> 6;
  const int wm = (w & 1) * 64, wn = (w >> 1) * 64;
  const int lm = l & 15, lq = l >> 4;
  const int srow = t >> 1, skc = (t & 1) * 16;
  f32x4 acc[4][4] = {};
  for (int k0 = 0; k0 < Dd; k0 += 32) {
    {
      const unsigned short* src = XB + (size_t)(row0 + srow) * Dd + k0 + skc;
      *(uint4*)&sA[srow][skc] = *(const uint4*)src;
      *(uint4*)&sA[srow][skc + 8] = *(const uint4*)(src + 8);
    }
    {
      const unsigned short* srcB = WQT + (size_t)(col0 + srow) * Dd + k0 + skc;
      *(uint4*)&sB[srow][skc] = *(const uint4*)srcB;
      *(uint4*)&sB[srow][skc + 8] = *(const uint4*)(srcB + 8);
    }
    __syncthreads();
    f16x8 af[4], bfr[4];
#pragma unroll
    for (int i = 0; i < 4; i++) af[i] = *(const f16x8*)&sA[wm + 16 * i + lm][lq * 8];
#pragma unroll
    for (int j = 0; j < 4; j++) bfr[j] = *(const f16x8*)&sB[wn + 16 * j + lm][lq * 8];
    if (isqk) {
#pragma unroll
      for (int i = 0; i < 4; i++)
#pragma unroll
        for (int j = 0; j < 4; j++) acc[i][j] = MFMA16(bfr[i], af[j], acc[i][j]);
    } else {
#pragma unroll
      for (int i = 0; i < 4; i++)
#pragma unroll
        for (int j = 0; j < 4; j++) acc[i][j] = MFMA16(af[i], bfr[j], acc[i][j]);
    }
    __syncthreads();
  }
  if (isqk) {
#pragma unroll
    for (int jc = 0; jc < 4; jc++)
#pragma unroll
      for (int ir = 0; ir < 4; ir++) {
        unsigned short us[4];
#pragma unroll
        for (int r = 0; r < 4; r++) us[r] = f2h(acc[jc][ir][r]);
        *(uint2*)&sEp[(wm + 16 * ir + lm) * 136 + wn + 16 * jc + 4 * lq] = *(uint2*)us;
      }
    __syncthreads();
    const int row = t >> 1, half = t & 1;
    const unsigned short* src = &sEp[row * 136 + half * 64];
    unsigned short* dst = qkv + (size_t)(row0 + row) * QW + col0 + half * 64;
#pragma unroll
    for (int c = 0; c < 8; c++) *(uint4*)(dst + c * 8) = *(const uint4*)(src + c * 8);
  } else {
#pragma unroll
    for (int ir = 0; ir < 4; ir++)
#pragma unroll
      for (int jc = 0; jc < 4; jc++) {
        unsigned short us[4];
#pragma unroll
        for (int r = 0; r < 4; r++) us[r] = f2h(acc[ir][jc][r]);
        *(uint2*)&sEp[(wn + 16 * jc + lm) * 136 + wm + 16 * ir + 4 * lq] = *(uint2*)us;
      }
    __syncthreads();
    const int row = t >> 1, half = t & 1;
    const int gd = col0 - 2 * INNER + row;
    const int bq = row0 >> 10, mseq0 = row0 & 1023;
    const unsigned short* src = &sEp[row * 136 + half * 64];
    unsigned short* dst =
        vT + (((size_t)(bq * Hh + (gd >> 6)) * DH + (gd & 63)) << 10) + mseq0 + half * 64;
#pragma unroll
    for (int c = 0; c < 8; c++) *(uint4*)(dst + c * 8) = *(const uint4*)(src + c * 8);
  }
}

// ---------------- k_vsum --------------------------------------------------
__global__ __launch_bounds__(256) void k_vsum(const unsigned short* __restrict__ vT,
                                              float* __restrict__ vsum) {
  const int bg = blockIdx.x;
  const int d = threadIdx.x >> 2, qq = threadIdx.x & 3;
  __shared__ float red[64][4];
  const unsigned short* p = vT + ((size_t)bg * DH + d) * Nn + qq * 256;
  float s = 0.f;
  for (int m = 0; m < 256; m += 4) {
    uint2 rr = *(const uint2*)(p + m);
    s += h2f((unsigned short)(rr.x & 0xffff)) + h2f((unsigned short)(rr.x >> 16)) +
         h2f((unsigned short)(rr.y & 0xffff)) + h2f((unsigned short)(rr.y >> 16));
  }
  red[d][qq] = s;
  __syncthreads();
  if (threadIdx.x < 64)
    vsum[(size_t)bg * DH + threadIdx.x] =
        red[threadIdx.x][0] + red[threadIdx.x][1] + red[threadIdx.x][2] + red[threadIdx.x][3];
}

// ---------------- kA: rinv (R8 validated; zero LDS, zero barriers) ---------
// grid (b=8, nt=64); 512 thr = 8 waves, wave w = head w, n-tile 16.
__global__ __launch_bounds__(512, 2) void k_rsum(const unsigned short* __restrict__ qkv,
                                                 float* __restrict__ rinv) {
  const int b = blockIdx.x;
  const int n0 = blockIdx.y * 16;
  const int t = threadIdx.x;
  const int w = t >> 6, l = t & 63;
  const int lm = l & 15, lq = l >> 4;
  f16x8 qf[2];
  {
    const unsigned short* qp = qkv + (size_t)(b * Nn + n0 + lm) * QW + w * DH + lq * 8;
    qf[0] = *(const f16x8*)qp;
    qf[1] = *(const f16x8*)(qp + 32);
  }
  float psum[4] = {};
#pragma unroll 2
  for (int m0 = 0; m0 < Nn; m0 += 32) {
#pragma unroll
    for (int jm = 0; jm < 2; jm++) {
      const unsigned short* kp =
          qkv + (size_t)(b * Nn + m0 + 16 * jm + lm) * QW + INNER + w * DH + lq * 8;
      f16x8 k0 = *(const f16x8*)kp;
      f16x8 k1 = *(const f16x8*)(kp + 32);
      f32x4 lac = {};
      lac = MFMA16(qf[0], k0, lac);
      lac = MFMA16(qf[1], k1, lac);
#pragma unroll
      for (int r = 0; r < 4; r++) psum[r] += __expf(lac[r] * SCALE);
    }
  }
#pragma unroll
  for (int r = 0; r < 4; r++) {
    float s = psum[r];
    s += __shfl_xor(s, 1);
    s += __shfl_xor(s, 2);
    s += __shfl_xor(s, 4);
    s += __shfl_xor(s, 8);
    if (lm == 0) rinv[(size_t)(b * Hh + w) * Nn + n0 + lq * 4 + r] = 1.0f / s;
  }
}

// ---------------- kB: merged QK+mix+stats+PV, 2 barriers / 128 m -----------
// grid (b=8, nt=64); 512 thr = 8 waves; wave w = head (QK) = group (PV).
__global__ __launch_bounds__(512, 2) void k_fuse2(const unsigned short* __restrict__ qkv,
                                                  const unsigned short* __restrict__ vT,
                                                  const float* __restrict__ rinv,
                                                  const float* __restrict__ conv_w,
                                                  unsigned short* __restrict__ O1H,
                                                  float* __restrict__ stats) {
  __shared__ unsigned short sS[8][16][132];  // 33,792 B  [h][n][m] stride 132
  __shared__ unsigned short sU[8][16][132];  // 33,792 B  [g][n][m]
  __shared__ float sRedS[8][8];
  const int b = blockIdx.x;  // b fastest -> XCD-pinned qkv/vT
  const int n0 = blockIdx.y * 16;
  const int t = threadIdx.x;
  const int w = t >> 6, l = t & 63;
  const int lm = l & 15, lq = l >> 4;
  const int mn = t >> 5;        // mix: n row 0..15
  const int mj = t & 31;        // mix: m quad 0..31 (m = mj*4)
  float cw[64];
#pragma unroll
  for (int i = 0; i < 64; i++) cw[i] = conv_w[i];  // uniform -> SGPRs
  // Q frags: head w, n = n0+lm (B-operand; validated R9)
  f16x8 qf[2];
  {
    const unsigned short* qp = qkv + (size_t)(b * Nn + n0 + lm) * QW + w * DH + lq * 8;
    qf[0] = *(const f16x8*)qp;
    qf[1] = *(const f16x8*)(qp + 32);
  }
  const float rv = rinv[(size_t)(b * Hh + w) * Nn + n0 + lm];  // n = lm per lane
  f32x4 acc[4] = {};  // PV out: [dt], D[n=lq*4+r][d=dt*16+lm]
  float su2[8] = {};
  for (int it = 0; it < 8; it++) {
    const int m0 = it * 128;
    // ---- QK phase: 8 jm-tiles of 16 m; D[m][n] swapped; rinv folded ----
#pragma unroll
    for (int jm = 0; jm < 8; jm++) {
      const unsigned short* kp =
          qkv + (size_t)(b * Nn + m0 + jm * 16 + lm) * QW + INNER + w * DH + lq * 8;
      f16x8 k0 = *(const f16x8*)kp;
      f16x8 k1 = *(const f16x8*)(kp + 32);
      f32x4 lac = {};
      lac = MFMA16(k0, qf[0], lac);  // D[m=jm*16+lq*4+r][n=lm]
      lac = MFMA16(k1, qf[1], lac);
      unsigned short us[4];
#pragma unroll
      for (int r = 0; r < 4; r++) us[r] = f2h(__expf(lac[r] * SCALE) * rv);
      *(uint2*)&sS[w][lm][jm * 16 + lq * 4] = *(uint2*)us;
    }
    __syncthreads();  // sS complete (also: prev PV's sU reads are done)
    // ---- mix phase: thread owns (n=mn, m=mj*4..+3) across all h,g ----
    {
      float f[8][4];
#pragma unroll
      for (int h = 0; h < 8; h++) {
        uint2 pk = *(const uint2*)&sS[h][mn][mj * 4];
        f[h][0] = h2f((unsigned short)(pk.x & 0xffff));
        f[h][1] = h2f((unsigned short)(pk.x >> 16));
        f[h][2] = h2f((unsigned short)(pk.y & 0xffff));
        f[h][3] = h2f((unsigned short)(pk.y >> 16));
      }
#pragma unroll
      for (int g = 0; g < 8; g++) {
        float u0 = 0.f, u1 = 0.f, u2 = 0.f, u3 = 0.f;
#pragma unroll
        for (int h = 0; h < 8; h++) {
          const float c = cw[g * 8 + h];
          u0 += c * f[h][0];
          u1 += c * f[h][1];
          u2 += c * f[h][2];
          u3 += c * f[h][3];
        }
        su2[g] += u0 * u0 + u1 * u1 + u2 * u2 + u3 * u3;
        unsigned short us[4] = {f2h(u0), f2h(u1), f2h(u2), f2h(u3)};
        *(uint2*)&sU[g][mn][mj * 4] = *(uint2*)us;
      }
    }
    __syncthreads();  // sU complete (also: QK's sS writes next iter are safe)
    // ---- PV phase: A = sU[w] (native A-frag layout), B = vT from L2 ----
#pragma unroll
    for (int ks = 0; ks < 4; ks++) {
      f16x8 uf = *(const f16x8*)&sU[w][lm][ks * 32 + lq * 8];
#pragma unroll
      for (int dt = 0; dt < 4; dt++) {
        const unsigned short* vp =
            vT + (((size_t)(b * Hh + w) * DH + dt * 16 + lm) << 10) + m0 + ks * 32 + lq * 8;
        f16x8 vf = *(const f16x8*)vp;
        acc[dt] = MFMA16(uf, vf, acc[dt]);  // D[n=lq*4+r][d=dt*16+lm]
      }
    }
  }
  // O1H write (fp16): n = n0+lq*4+r, d = dt*16+lm
#pragma unroll
  for (int dt = 0; dt < 4; dt++)
#pragma unroll
    for (int r = 0; r < 4; r++)
      O1H[((size_t)(b * Hh + w) * Nn + n0 + lq * 4 + r) * DH + dt * 16 + lm] =
          f2h(acc[dt][r]);
  // stats: per-wave reduce su2[g], then cross-wave via LDS + atomics
#pragma unroll
  for (int g = 0; g < 8; g++) {
    float q = su2[g];
    for (int off = 32; off; off >>= 1) q += __shfl_down(q, off);
    if (l == 0) sRedS[w][g] = q;
  }
  __syncthreads();
  if (t < 8) {
    float s = 0.f;
#pragma unroll
    for (int ww = 0; ww < 8; ww++) s += sRedS[ww][t];
    atomicAdd(&stats[t], s);
  }
}

// ---------------- K3: alpha/const (E[u] analytic; R9-validated) ------------
__global__ void k_alpha(const float* __restrict__ stats, const float* __restrict__ conv_w,
                        const float* __restrict__ bn_gamma,
                        const float* __restrict__ bn_beta, float* __restrict__ ac) {
  const int g = threadIdx.x;
  if (g < 8) {
    float csum = 0.f;
#pragma unroll
    for (int h = 0; h < 8; h++) csum += conv_w[g * 8 + h];
    const float Eu = csum / (float)Nn;  // softmax rows sum to 1
    const float cnt = (float)Bz * (float)Nn * (float)Nn;
    float Eu2 = stats[g] / cnt;
    float inv = rsqrtf(Eu2 - Eu * Eu + BN_EPS);
    float alpha = bn_gamma[g] * inv;
    ac[g] = alpha;
    ac[8 + g] = bn_beta[g] - Eu * alpha;
  }
}

// ---------------- K4: out = affine(O1H) @ w_out + b_out (fp16 MFMA) --------
// BN affine (alpha*O1 + c*vsum) fused into A-staging (R3-validated pattern).
__global__ __launch_bounds__(256) void k_out(const unsigned short* __restrict__ O1H,
                                             const float* __restrict__ vsum,
                                             const float* __restrict__ ac,
                                             const unsigned short* __restrict__ WOT,
                                             const float* __restrict__ bout,
                                             float* __restrict__ out) {
  __shared__ unsigned short sA[128][40];
  __shared__ unsigned short sB[128][40];
  __shared__ float sAl[16];
  const int t = threadIdx.x;
  if (t < 16) sAl[t] = ac[t];
  const int col0 = blockIdx.x * 128, row0 = blockIdx.y * 128;
  const int l = t & 63, w = t >> 6;
  const int wm = (w & 1) * 64, wn = (w >> 1) * 64;
  const int lm = l & 15, lq = l >> 4;
  const int srow = t >> 1, skc = (t & 1) * 16;
  const int b = row0 >> 10;
  const int nn = (row0 + srow) & 1023;
  f32x4 acc[4][4] = {};
  __syncthreads();
  for (int k0 = 0; k0 < INNER; k0 += 32) {
    {  // A: affine(O1H) -> fp16
      const int k = k0 + skc;
      const int g = k >> 6, dd = k & 63;
      const float al = sAl[g], cc = sAl[8 + g];
      const unsigned short* op = O1H + ((size_t)(b * Hh + g) * Nn + nn) * DH + dd;
      const float* vp = vsum + (size_t)(b * Hh + g) * DH + dd;
      uint4 o0 = *(const uint4*)op;
      uint4 o1 = *(const uint4*)(op + 8);
      unsigned short tmp[16];
      const unsigned* ow = (const unsigned*)&o0;
#pragma unroll
      for (int c = 0; c < 4; c++) {
        float v0 = vp[c * 2], v1 = vp[c * 2 + 1];
        tmp[c * 2] = f2h(al * h2f((unsigned short)(ow[c] & 0xffff)) + cc * v0);
        tmp[c * 2 + 1] = f2h(al * h2f((unsigned short)(ow[c] >> 16)) + cc * v1);
      }
      const unsigned* ow1 = (const unsigned*)&o1;
#pragma unroll
      for (int c = 0; c < 4; c++) {
        float v0 = vp[8 + c * 2], v1 = vp[8 + c * 2 + 1];
        tmp[8 + c * 2] = f2h(al * h2f((unsigned short)(ow1[c] & 0xffff)) + cc * v0);
        tmp[8 + c * 2 + 1] = f2h(al * h2f((unsigned short)(ow1[c] >> 16)) + cc * v1);
      }
      *(uint4*)&sA[srow][skc] = *(uint4*)tmp;
      *(uint4*)&sA[srow][skc + 8] = *(uint4*)(tmp + 8);
    }
    {
      const unsigned short* srcB = WOT + (size_t)(col0 + srow) * INNER + k0 + skc;
      *(uint4*)&sB[srow][skc] = *(const uint4*)srcB;
      *(uint4*)&sB[srow][skc + 8] = *(const uint4*)(srcB + 8);
    }
    __syncthreads();
    f16x8 af[4], bfr[4];
#pragma unroll
    for (int i = 0; i < 4; i++) af[i] = *(const f16x8*)&sA[wm + 16 * i + lm][lq * 8];
#pragma unroll
    for (int j = 0; j < 4; j++) bfr[j] = *(const f16x8*)&sB[wn + 16 * j + lm][lq * 8];
#pragma unroll
    for (int i = 0; i < 4; i++)
#pragma unroll
      for (int j = 0; j < 4; j++) acc[i][j] = MFMA16(af[i], bfr[j], acc[i][j]);
    __syncthreads();
  }
#pragma unroll
  for (int j = 0; j < 4; j++) {
    const int col = col0 + wn + 16 * j + lm;
    const float bo = bout[col];
#pragma unroll
    for (int i = 0; i < 4; i++) {
      const int rbase = row0 + wm + 16 * i + lq * 4;
#pragma unroll
      for (int r = 0; r < 4; r++) out[(size_t)(rbase + r) * Dd + col] = acc[i][j][r] + bo;
    }
  }
}

extern "C" void kernel_launch(void* const* d_in, const int* in_sizes, int n_in,
                              void* d_out, int out_size, void* d_ws, size_t ws_size,
                              hipStream_t stream) {
  const float* x = (const float*)d_in[0];
  const float* w_qkv = (const float*)d_in[1];
  const float* conv_w = (const float*)d_in[2];
  // d_in[3] = conv_b : cancels in train-mode BN.
  const float* bn_gamma = (const float*)d_in[4];
  const float* bn_beta = (const float*)d_in[5];
  const float* w_out = (const float*)d_in[6];
  const float* b_out = (const float*)d_in[7];
  char* ws = (char*)d_ws;
  unsigned short* XB = (unsigned short*)(ws + WB_XB);
  unsigned short* QKV = (unsigned short*)(ws + WB_QKV);
  unsigned short* VT = (unsigned short*)(ws + WB_VT);
  unsigned short* O1H = (unsigned short*)(ws + WB_O1H);
  unsigned short* WQT = (unsigned short*)(ws + WB_WQT);
  unsigned short* WOT = (unsigned short*)(ws + WB_WOT);
  float* RINV = (float*)(ws + WB_RINV);
  float* VSUM = (float*)(ws + WB_VSUM);
  float* STATS = (float*)(ws + WB_STATS);
  float* AC = (float*)(ws + WB_AC);

  hipMemsetAsync(STATS, 0, 64, stream);
  k_xbf<<<2048, 256, 0, stream>>>(x, XB);
  k_transpose<<<dim3(48, 16), 256, 0, stream>>>(w_qkv, WQT, 512, 1536);
  k_transpose<<<dim3(16, 16), 256, 0, stream>>>(w_out, WOT, 512, 512);
  k_qkv<<<dim3(12, 64), 256, 34816, stream>>>(XB, WQT, QKV, VT);
  k_vsum<<<64, 256, 0, stream>>>(VT, VSUM);
  k_rsum<<<dim3(8, 64), 512, 0, stream>>>(QKV, RINV);
  k_fuse2<<<dim3(8, 64), 512, 0, stream>>>(QKV, VT, RINV, conv_w, O1H, STATS);
  k_alpha<<<1, 64, 0, stream>>>(STATS, conv_w, bn_gamma, bn_beta, AC);
  k_out<<<dim3(4, 64), 256, 0, stream>>>(O1H, VSUM, AC, WOT, b_out, (float*)d_out);
}